// Round 9
// baseline (28833.582 us; speedup 1.0000x reference)
//
#include <hip/hip_runtime.h>
#include <math.h>

// Problem constants
#define B_   64
#define U_   1024
#define E_   512
#define D_   640
#define L4_  2560
#define TC   64          // time-chunk length
#define NCH  16          // number of chunks (TC*NCH == U_)
#define NBLK 160         // persistent blocks (4 d's each); 160 <= 256 CUs -> co-resident
#define SUBQ (NBLK / 8)  // blocks per sub-counter
#define UPITCH 644       // U_lds row pitch (floats): 2576B = 16B mod 128B -> bank-spread

// ---------------------------------------------------------------------------
// GEMM: C[t][n][b] = bias[n] + sum_k A[m][k] * W[k][n],  m = t*64 + b
// (unchanged, harness-verified)
// ---------------------------------------------------------------------------
template <int MODE>
__global__ __launch_bounds__(256) void gemm_kernel(
    const float* __restrict__ A,        // MODE0: embed [V][E]; MODE1: h0c [TC][640][64]
    const int*   __restrict__ targets,  // [B][U], used in MODE0
    const float* __restrict__ Wm,       // [K][2560]
    const float* __restrict__ bias,     // [2560]
    float* __restrict__ xz,             // [TC][2560][64]
    int K, int t0)
{
    const int tid = threadIdx.x;
    const int m0 = blockIdx.x * 128;
    const int n0 = blockIdx.y * 128;

    __shared__ float As[8][132];
    __shared__ float Bs[8][132];

    float acc[8][8];
#pragma unroll
    for (int i = 0; i < 8; ++i)
#pragma unroll
        for (int j = 0; j < 8; ++j) acc[i][j] = 0.f;

    const float* a_ptr;
    int a_ml = 0, a_kq = 0, a_k = 0;
    if (MODE == 0) {
        a_ml = tid & 127;
        a_kq = (tid >> 7) * 4;
        int m  = m0 + a_ml;
        int b  = m & 63;
        int tl = m >> 6;
        int idx = targets[b * U_ + t0 + tl];
        a_ptr = A + (size_t)idx * E_ + a_kq;
    } else {
        a_k  = tid >> 5;
        a_ml = (tid & 31) * 4;
        int m  = m0 + a_ml;
        int b  = m & 63;
        int tl = m >> 6;
        a_ptr = A + (size_t)tl * (D_ * 64) + (size_t)a_k * 64 + b;
    }
    const int b_k  = tid >> 5;
    const int b_n4 = (tid & 31) * 4;

    const int tx = tid & 15;
    const int ty = tid >> 4;

    for (int k0 = 0; k0 < K; k0 += 8) {
        if (MODE == 0) {
            float4 av = *(const float4*)(a_ptr + k0);
            As[a_kq + 0][a_ml] = av.x;
            As[a_kq + 1][a_ml] = av.y;
            As[a_kq + 2][a_ml] = av.z;
            As[a_kq + 3][a_ml] = av.w;
        } else {
            float4 av = *(const float4*)(a_ptr + (size_t)k0 * 64);
            *(float4*)&As[a_k][a_ml] = av;
        }
        {
            float4 bv = *(const float4*)(Wm + (size_t)(k0 + b_k) * L4_ + n0 + b_n4);
            *(float4*)&Bs[b_k][b_n4] = bv;
        }
        __syncthreads();

#pragma unroll
        for (int k = 0; k < 8; ++k) {
            float af[8], bf[8];
            *(float4*)&af[0] = *(const float4*)&As[k][ty * 8];
            *(float4*)&af[4] = *(const float4*)&As[k][ty * 8 + 4];
            *(float4*)&bf[0] = *(const float4*)&Bs[k][tx * 8];
            *(float4*)&bf[4] = *(const float4*)&Bs[k][tx * 8 + 4];
#pragma unroll
            for (int i = 0; i < 8; ++i)
#pragma unroll
                for (int j = 0; j < 8; ++j) acc[i][j] += af[i] * bf[j];
        }
        __syncthreads();
    }

#pragma unroll
    for (int i = 0; i < 8; ++i) {
        int m  = m0 + ty * 8 + i;
        int tl = m >> 6;
        int b  = m & 63;
        float* outp = xz + (size_t)tl * (L4_ * 64) + b;
#pragma unroll
        for (int j = 0; j < 8; ++j) {
            int n = n0 + tx * 8 + j;
            outp[(size_t)n * 64] = acc[i][j] + bias[n];
        }
    }
}

// ---------------------------------------------------------------------------
// Pre-transpose recurrent weights, N-MAJOR per block:
//   Up[g][n16][k] = Uw[k][gate*640 + (g*4+dd)],  n16 = dd*4 + gate
// Block g's slice (16 rows x 640 k = 40 KB) is staged to LDS once per seq
// dispatch and read per-lane.
// ---------------------------------------------------------------------------
__global__ __launch_bounds__(256) void prep_up_kernel(
    const float* __restrict__ U0w, const float* __restrict__ U1w,
    float* __restrict__ Up0, float* __restrict__ Up1)
{
    const int k = blockIdx.x;                       // 0..639
    const float* Uw = blockIdx.y ? U1w : U0w;
    float*       Up = blockIdx.y ? Up1 : Up0;
    for (int d = threadIdx.x; d < D_; d += 256) {   // coalesced reads over d
        const int g  = d >> 2;
        const int dd = d & 3;
#pragma unroll
        for (int gate = 0; gate < 4; ++gate) {
            float v = Uw[(size_t)k * L4_ + gate * 640 + d];
            Up[((size_t)g * 16 + dd * 4 + gate) * 640 + k] = v;
        }
    }
}

// ---------------------------------------------------------------------------
// LLC write-through store (sc1, agent scope): publishes h to the LLC so other
// XCDs' L2 fills (of this never-before-read address) get fresh data.
// ---------------------------------------------------------------------------
__device__ __forceinline__ void stg_llc(float* p, float v) {
    __hip_atomic_store(p, v, __ATOMIC_RELAXED, __HIP_MEMORY_SCOPE_AGENT);
}

// ---------------------------------------------------------------------------
// Two-level, monotonic (no-reset) grid barrier. Proven in rounds 3/6/7.
// vmcnt(0) before arrival drains the sc1 h-store to the LLC; readers touch
// per-step-unique addresses afterwards, so plain cached loads are safe.
// ---------------------------------------------------------------------------
__device__ __forceinline__ void grid_barrier(unsigned* bar, unsigned done)
{
    asm volatile("s_waitcnt vmcnt(0)" ::: "memory");
    __syncthreads();
    if (threadIdx.x == 0) {
        unsigned* sub    = bar + ((blockIdx.x & 7) << 5);   // 128B-separated lines
        unsigned* master = bar + (8 << 5);
        unsigned a = __hip_atomic_fetch_add(sub, 1u, __ATOMIC_RELAXED, __HIP_MEMORY_SCOPE_AGENT);
        if (a == done * SUBQ - 1u)
            __hip_atomic_fetch_add(master, 1u, __ATOMIC_RELAXED, __HIP_MEMORY_SCOPE_AGENT);
        const unsigned tgt = done * 8u;
        while (__hip_atomic_load(master, __ATOMIC_RELAXED, __HIP_MEMORY_SCOPE_AGENT) < tgt)
            __builtin_amdgcn_s_sleep(1);
    }
    __syncthreads();
}

// ---------------------------------------------------------------------------
// Persistent LSTM sequence kernel, round 8 geometry (+ U_lds bank pad).
// Grid: 160 blocks x 256 threads (4 waves = 4 k-slices of 160).
// Lane: n_grp = lane>>3 (8 groups x 2 rows), b_grp = lane&7 (8 groups x 8 b).
// Thread tile 2 rows x 8 batch (16 acc).
// r7 post-mortem: LDS is per-CU; r7's 1280 bcast ds_read_b128/block/step
// (12cyc each = 6.4us) was the wall, plus 26MB/step of sc1 h-reads at LLC.
//  - U now n_t=2: 320 b128/block/step -> DS ~1.6us < VALU 2.1us.
//  - U_lds rows padded to 644 floats: row stride 2576B = 16B (mod 128B), so
//    the 8 distinct per-lane row addresses spread across banks (640-float
//    rows would be 8-way same-bank congruent).
//  - h read via PLAIN cached loads from hc_out[tl-1] (per-step-unique addr;
//    writer publishes with one sc1 store; L2 fill comes from LLC = fresh;
//    ~20 blocks/XCD share one L2 copy -> LLC traffic 26MB -> ~1.3MB/step).
//  - 3-stage software pipeline on h (4k x 8b = 32-reg buffers) covers L2 lat.
// ---------------------------------------------------------------------------
__global__ __launch_bounds__(256) void lstm_seq_kernel(
    const float* __restrict__ xz,      // [TC][2560][64]
    const float* __restrict__ Upg,     // [160][16][640] pre-transposed (n-major)
    const float* __restrict__ hinit,   // [640][64] carry-in (prev chunk tail / zeros)
    float* __restrict__ c_st,          // [640][64]
    const int* __restrict__ lens,      // [64]
    float* __restrict__ hc_out,        // [TC][640][64]; doubles as h publish chain
    int t0,
    unsigned* __restrict__ bar,
    unsigned bar_base)
{
    const int tid  = threadIdx.x;
    const int d0   = blockIdx.x * 4;
    const int ks   = tid >> 6;               // 0..3 (wave = k-slice)
    const int kbeg = ks * 160;
    const int lane   = tid & 63;
    const int n_base = (lane >> 3) * 2;      // 0,2,..,14
    const int b0     = (lane & 7) * 8;       // 0,8,..,56

    __shared__ float U_lds[16 * UPITCH];     // ~41 KB (padded rows)
    __shared__ float red[64][64];            // 16 KB: [n16*4 + ks][b]

    // stage this block's U slice to LDS once (row-padded copy, float4 units:
    // 160 float4 per source row -> dest row pitch 161 float4)
    {
        const float4* upg = (const float4*)(Upg + (size_t)blockIdx.x * (640 * 16));
        float4* udst = (float4*)U_lds;
#pragma unroll
        for (int it = 0; it < 10; ++it) {
            const int e = it * 256 + tid;    // 0..2559 (float4 index)
            const int r = e / 160;
            const int c = e - r * 160;
            udst[r * (UPITCH / 4) + c] = upg[e];
        }
    }

    // epilogue-private state: all 256 threads own one (d,b) cell
    const int ed = d0 + (tid >> 6);
    const int eb = tid & 63;
    float c_reg   = c_st[ed * 64 + eb];
    const int len_b = lens[eb];

    __syncthreads();                         // U_lds ready

    float acc[16];
    float HA[32], HB[32], HC[32];            // 4k x 8b each
    float UA[8],  UB[8],  UC[8];             // 4k x 2 rows each

#define HLOAD(HH)                                                           \
    _Pragma("unroll")                                                       \
    for (int j = 0; j < 4; ++j) {                                           \
        *(float4*)&HH[j * 8 + 0] = *(const float4*)(hrun + j * 64);         \
        *(float4*)&HH[j * 8 + 4] = *(const float4*)(hrun + j * 64 + 4);     \
    }                                                                       \
    hrun += 256;

#define ULOAD(UU)                                                           \
    *(float4*)&UU[0] = *(const float4*)(urun);                              \
    *(float4*)&UU[4] = *(const float4*)(urun + UPITCH);                     \
    urun += 4;

#define FMAG(HH, UU)                                                        \
    _Pragma("unroll")                                                       \
    for (int j = 0; j < 4; ++j)                                             \
        _Pragma("unroll")                                                   \
        for (int i = 0; i < 2; ++i)                                         \
            _Pragma("unroll")                                               \
            for (int q = 0; q < 8; ++q)                                     \
                acc[i * 8 + q] += UU[i * 4 + j] * HH[j * 8 + q];

#pragma unroll 1
    for (int tl = 0; tl < TC; ++tl) {
        const int t = t0 + tl;
        const float* hprev = (tl == 0) ? hinit
                           : hc_out + (size_t)(tl - 1) * (D_ * 64);
        float*       hcur  = hc_out + (size_t)tl * (D_ * 64);

        // prefetch epilogue operands early -> latency hidden under k-loop
        float xzv[4];
        {
            const float* xzp = xz + (size_t)tl * (L4_ * 64) + eb;
#pragma unroll
            for (int g = 0; g < 4; ++g)
                xzv[g] = xzp[(size_t)(ed + 640 * g) * 64];
        }
        const float hp_epi = hprev[ed * 64 + eb];

#pragma unroll
        for (int i = 0; i < 16; ++i) acc[i] = 0.f;

        const float* hrun = hprev + (size_t)kbeg * 64 + b0;
        const float* urun = &U_lds[n_base * UPITCH + kbeg];

        // 3-stage pipeline over 40 groups of 4 k
        HLOAD(HA) ULOAD(UA)
        HLOAD(HB) ULOAD(UB)
        HLOAD(HC) ULOAD(UC)
#pragma unroll 1
        for (int t3 = 0; t3 < 12; ++t3) {
            FMAG(HA, UA) HLOAD(HA) ULOAD(UA)
            FMAG(HB, UB) HLOAD(HB) ULOAD(UB)
            FMAG(HC, UC) HLOAD(HC) ULOAD(UC)
        }
        FMAG(HA, UA) HLOAD(HA) ULOAD(UA)     // compute g=36, load g=39
        FMAG(HB, UB)                          // g=37
        FMAG(HC, UC)                          // g=38
        FMAG(HA, UA)                          // g=39

        // partials -> red
#pragma unroll
        for (int i = 0; i < 2; ++i) {
            *(float4*)&red[((n_base + i) << 2) | ks][b0]     = *(float4*)&acc[i * 8];
            *(float4*)&red[((n_base + i) << 2) | ks][b0 + 4] = *(float4*)&acc[i * 8 + 4];
        }
        __syncthreads();

        {
            const int dd = tid >> 6;
            float z[4];
#pragma unroll
            for (int g = 0; g < 4; ++g) {
                const int r = ((dd * 4 + g) << 2);
                z[g] = red[r][eb] + red[r + 1][eb] + red[r + 2][eb] + red[r + 3][eb]
                     + xzv[g];
            }
            float ig = 1.f / (1.f + __expf(-z[0]));
            float fg = 1.f / (1.f + __expf(-z[1]));
            float gg = tanhf(z[2]);
            float og = 1.f / (1.f + __expf(-z[3]));
            float c_new = fg * c_reg + ig * gg;
            float h_new = og * tanhf(c_new);
            bool msk = t < len_b;
            float h_out = msk ? h_new : hp_epi;
            c_reg = msk ? c_new : c_reg;
            stg_llc(hcur + ed * 64 + eb, h_out);   // single sc1 publish store
        }

        if (tl != TC - 1)
            grid_barrier(bar, bar_base + (unsigned)tl + 1u);
    }
    c_st[ed * 64 + eb] = c_reg;             // persist c for next chunk
#undef HLOAD
#undef ULOAD
#undef FMAG
}

// ---------------------------------------------------------------------------
// Transpose chunk h1c [tl][d][b] -> out [b][t0+tl][d]   (unchanged)
// ---------------------------------------------------------------------------
__global__ __launch_bounds__(256) void transpose_kernel(
    const float* __restrict__ h1c, float* __restrict__ out, int t0)
{
    const int tl   = blockIdx.x;
    const int dblk = blockIdx.y;
    __shared__ float tile[64][65];

    const int r  = threadIdx.x >> 2;
    const int cq = threadIdx.x & 3;

    const float* src = h1c + (size_t)tl * (D_ * 64) + (size_t)(dblk * 64 + r) * 64 + cq * 16;
#pragma unroll
    for (int j = 0; j < 4; ++j) {
        float4 v = *(const float4*)(src + j * 4);
        tile[r][cq * 16 + j * 4 + 0] = v.x;
        tile[r][cq * 16 + j * 4 + 1] = v.y;
        tile[r][cq * 16 + j * 4 + 2] = v.z;
        tile[r][cq * 16 + j * 4 + 3] = v.w;
    }
    __syncthreads();

    float* dst = out + (size_t)r * (U_ * D_) + (size_t)(t0 + tl) * D_ + dblk * 64 + cq * 16;
#pragma unroll
    for (int j = 0; j < 4; ++j) {
        float4 w;
        w.x = tile[cq * 16 + j * 4 + 0][r];
        w.y = tile[cq * 16 + j * 4 + 1][r];
        w.z = tile[cq * 16 + j * 4 + 2][r];
        w.w = tile[cq * 16 + j * 4 + 3][r];
        *(float4*)(dst + j * 4) = w;
    }
}

// ---------------------------------------------------------------------------
extern "C" void kernel_launch(void* const* d_in, const int* in_sizes, int n_in,
                              void* d_out, int out_size, void* d_ws, size_t ws_size,
                              hipStream_t stream)
{
    const int*   targets = (const int*)d_in[0];
    const int*   lens    = (const int*)d_in[1];
    const float* embed   = (const float*)d_in[2];
    const float* W0      = (const float*)d_in[3];
    const float* U0      = (const float*)d_in[4];
    const float* b0      = (const float*)d_in[5];
    const float* W1      = (const float*)d_in[6];
    const float* U1      = (const float*)d_in[7];
    const float* b1      = (const float*)d_in[8];
    float* out = (float*)d_out;
    float* ws  = (float*)d_ws;

    // workspace layout (floats)
    float* xz  = ws;                                   // TC*2560*64 = 10,485,760
    float* h0c = xz  + (size_t)TC * L4_ * 64;          // TC*640*64  =  2,621,440
    float* h1c = h0c + (size_t)TC * D_ * 64;           // TC*640*64
    float* st  = h1c + (size_t)TC * D_ * 64;           // 6 * 40,960 state buffers
    float* hzero = st;                                 // zero carry-in for chunk 0
    float* c0  = st + 2 * 40960;
    float* c1  = st + 5 * 40960;
    unsigned* bar = (unsigned*)(st + 6 * 40960);       // 512 uints (9 x 128B lines used)
    float* Up0 = st + 6 * 40960 + 512;                 // 640*2560 (64B-aligned)
    float* Up1 = Up0 + (size_t)D_ * L4_;               // 640*2560
    // total ~19.25M floats ~= 77 MB (same as verified layout)

    // zero-init states + barrier words (ws is poisoned before every call)
    hipMemsetAsync(st, 0, (size_t)6 * 40960 * sizeof(float) + 2048, stream);

    // one-time recurrent-weight transpose for both layers (n-major layout)
    prep_up_kernel<<<dim3(D_, 2), dim3(256), 0, stream>>>(U0, U1, Up0, Up1);

    const dim3 gemm_grid(TC * 64 / 128, L4_ / 128);    // (32, 20)
    const dim3 blk(256);

    unsigned launch_idx = 0;
    for (int ch = 0; ch < NCH; ++ch) {
        const int t0 = ch * TC;
        const float* hinit0 = (ch == 0) ? hzero : h0c + (size_t)(TC - 1) * (D_ * 64);
        const float* hinit1 = (ch == 0) ? hzero : h1c + (size_t)(TC - 1) * (D_ * 64);

        // layer 0 input transform: xz = embed[targets] @ W0 + b0
        gemm_kernel<0><<<gemm_grid, blk, 0, stream>>>(embed, targets, W0, b0, xz, E_, t0);

        // layer 0: 64 timesteps in one persistent launch
        lstm_seq_kernel<<<dim3(NBLK), blk, 0, stream>>>(
            xz, Up0, hinit0, c0, lens, h0c, t0, bar, launch_idx * 63u);
        ++launch_idx;

        // layer 1 input transform: xz = h0c @ W1 + b1
        gemm_kernel<1><<<gemm_grid, blk, 0, stream>>>(h0c, targets, W1, b1, xz, D_, t0);

        // layer 1: 64 timesteps in one persistent launch
        lstm_seq_kernel<<<dim3(NBLK), blk, 0, stream>>>(
            xz, Up1, hinit1, c1, lens, h1c, t0, bar, launch_idx * 63u);
        ++launch_idx;

        // emit chunk to output
        transpose_kernel<<<dim3(TC, 10), blk, 0, stream>>>(h1c, out, t0);
    }
}

// Round 10
// 21490.773 us; speedup vs baseline: 1.3417x; 1.3417x over previous
//
#include <hip/hip_runtime.h>
#include <math.h>

// Problem constants
#define B_   64
#define U_   1024
#define E_   512
#define D_   640
#define L4_  2560
#define TC   64          // time-chunk length
#define NCH  16          // number of chunks (TC*NCH == U_)
#define NBLK 160         // persistent blocks (4 d's each); 160 <= 256 CUs -> co-resident
#define SUBQ (NBLK / 8)  // blocks per sub-counter

// ---------------------------------------------------------------------------
// GEMM: C[t][n][b] = bias[n] + sum_k A[m][k] * W[k][n],  m = t*64 + b
// (unchanged, harness-verified)
// ---------------------------------------------------------------------------
template <int MODE>
__global__ __launch_bounds__(256) void gemm_kernel(
    const float* __restrict__ A,        // MODE0: embed [V][E]; MODE1: h0c [TC][640][64]
    const int*   __restrict__ targets,  // [B][U], used in MODE0
    const float* __restrict__ Wm,       // [K][2560]
    const float* __restrict__ bias,     // [2560]
    float* __restrict__ xz,             // [TC][2560][64]
    int K, int t0)
{
    const int tid = threadIdx.x;
    const int m0 = blockIdx.x * 128;
    const int n0 = blockIdx.y * 128;

    __shared__ float As[8][132];
    __shared__ float Bs[8][132];

    float acc[8][8];
#pragma unroll
    for (int i = 0; i < 8; ++i)
#pragma unroll
        for (int j = 0; j < 8; ++j) acc[i][j] = 0.f;

    const float* a_ptr;
    int a_ml = 0, a_kq = 0, a_k = 0;
    if (MODE == 0) {
        a_ml = tid & 127;
        a_kq = (tid >> 7) * 4;
        int m  = m0 + a_ml;
        int b  = m & 63;
        int tl = m >> 6;
        int idx = targets[b * U_ + t0 + tl];
        a_ptr = A + (size_t)idx * E_ + a_kq;
    } else {
        a_k  = tid >> 5;
        a_ml = (tid & 31) * 4;
        int m  = m0 + a_ml;
        int b  = m & 63;
        int tl = m >> 6;
        a_ptr = A + (size_t)tl * (D_ * 64) + (size_t)a_k * 64 + b;
    }
    const int b_k  = tid >> 5;
    const int b_n4 = (tid & 31) * 4;

    const int tx = tid & 15;
    const int ty = tid >> 4;

    for (int k0 = 0; k0 < K; k0 += 8) {
        if (MODE == 0) {
            float4 av = *(const float4*)(a_ptr + k0);
            As[a_kq + 0][a_ml] = av.x;
            As[a_kq + 1][a_ml] = av.y;
            As[a_kq + 2][a_ml] = av.z;
            As[a_kq + 3][a_ml] = av.w;
        } else {
            float4 av = *(const float4*)(a_ptr + (size_t)k0 * 64);
            *(float4*)&As[a_k][a_ml] = av;
        }
        {
            float4 bv = *(const float4*)(Wm + (size_t)(k0 + b_k) * L4_ + n0 + b_n4);
            *(float4*)&Bs[b_k][b_n4] = bv;
        }
        __syncthreads();

#pragma unroll
        for (int k = 0; k < 8; ++k) {
            float af[8], bf[8];
            *(float4*)&af[0] = *(const float4*)&As[k][ty * 8];
            *(float4*)&af[4] = *(const float4*)&As[k][ty * 8 + 4];
            *(float4*)&bf[0] = *(const float4*)&Bs[k][tx * 8];
            *(float4*)&bf[4] = *(const float4*)&Bs[k][tx * 8 + 4];
#pragma unroll
            for (int i = 0; i < 8; ++i)
#pragma unroll
                for (int j = 0; j < 8; ++j) acc[i][j] += af[i] * bf[j];
        }
        __syncthreads();
    }

#pragma unroll
    for (int i = 0; i < 8; ++i) {
        int m  = m0 + ty * 8 + i;
        int tl = m >> 6;
        int b  = m & 63;
        float* outp = xz + (size_t)tl * (L4_ * 64) + b;
#pragma unroll
        for (int j = 0; j < 8; ++j) {
            int n = n0 + tx * 8 + j;
            outp[(size_t)n * 64] = acc[i][j] + bias[n];
        }
    }
}

// ---------------------------------------------------------------------------
// Pre-transpose recurrent weights, K-MAJOR per block:
//   Up[g][k][n16] = Uw[k][gate*640 + (g*4+dd)],  n16 = dd*4 + gate
// Block g's slice (640 k x 16 rows = 40 KB) is staged to LDS once per seq
// dispatch; per k one ds_read_b128 at [k][n_base] yields a lane's 4 n-rows.
// Bank check: dword addr = 16k + n_base, n_base in {0,4,8,12} -> 4 distinct
// bank-quads per instruction, 16-way broadcast each -> conflict-free.
// ---------------------------------------------------------------------------
__global__ __launch_bounds__(256) void prep_up_kernel(
    const float* __restrict__ U0w, const float* __restrict__ U1w,
    float* __restrict__ Up0, float* __restrict__ Up1)
{
    const int k = blockIdx.x;                       // 0..639
    const float* Uw = blockIdx.y ? U1w : U0w;
    float*       Up = blockIdx.y ? Up1 : Up0;
    for (int d = threadIdx.x; d < D_; d += 256) {   // coalesced reads over d
        const int g  = d >> 2;
        const int dd = d & 3;
#pragma unroll
        for (int gate = 0; gate < 4; ++gate) {
            float v = Uw[(size_t)k * L4_ + gate * 640 + d];
            Up[((size_t)g * 640 + k) * 16 + dd * 4 + gate] = v;
        }
    }
}

// ---------------------------------------------------------------------------
// LLC write-through store (sc1, agent scope): publishes h to the LLC so other
// XCDs' L2 fills (of this never-before-read address) get fresh data.
// (Scheme harness-verified in round 9: passed with absmax 6.1e-05.)
// ---------------------------------------------------------------------------
__device__ __forceinline__ void stg_llc(float* p, float v) {
    __hip_atomic_store(p, v, __ATOMIC_RELAXED, __HIP_MEMORY_SCOPE_AGENT);
}

// ---------------------------------------------------------------------------
// Two-level, monotonic (no-reset) grid barrier. Proven rounds 3/6/7/9.
// ---------------------------------------------------------------------------
__device__ __forceinline__ void grid_barrier(unsigned* bar, unsigned done)
{
    asm volatile("s_waitcnt vmcnt(0)" ::: "memory");
    __syncthreads();
    if (threadIdx.x == 0) {
        unsigned* sub    = bar + ((blockIdx.x & 7) << 5);   // 128B-separated lines
        unsigned* master = bar + (8 << 5);
        unsigned a = __hip_atomic_fetch_add(sub, 1u, __ATOMIC_RELAXED, __HIP_MEMORY_SCOPE_AGENT);
        if (a == done * SUBQ - 1u)
            __hip_atomic_fetch_add(master, 1u, __ATOMIC_RELAXED, __HIP_MEMORY_SCOPE_AGENT);
        const unsigned tgt = done * 8u;
        while (__hip_atomic_load(master, __ATOMIC_RELAXED, __HIP_MEMORY_SCOPE_AGENT) < tgt)
            __builtin_amdgcn_s_sleep(1);
    }
    __syncthreads();
}

// ---------------------------------------------------------------------------
// Persistent LSTM sequence kernel, round 10: BALANCED 4x4 thread tile.
// Grid: 160 blocks x 256 threads (4 waves = 4 k-slices of 160).
// Lane: n_grp = lane>>4 (4 groups x 4 n-rows), b_grp = lane&15 (16 x 4 b).
// r9 post-mortem: (n2,b8) made h-VMEM the wall (1.31MB/CU-step reg writes,
// 8x lane-dup) and the red[] store pattern 8-16-way bank-conflicted (2.62M).
// r7 (n8,b2) was U-DS-walled (15.4k cyc). Balanced (n4,b4):
//   DS  = 640 b128/CU-step x 12cyc = 7680 cyc (U k-major, conflict-free)
//   VMEM= 655KB/CU-step reg-writes, 4x dup, 256B-coalesced    (~5120 cyc)
//   VALU= 5120 cyc
// -> separate pipes, each <= 3.2us; + barrier ~1.4us.
// red[] bank fix: col = b ^ (n_grp<<2) XOR-swizzle (bijective, f4-aligned,
// max 2-way aliasing = free); epilogue reads apply the same XOR with dd.
// ---------------------------------------------------------------------------
__global__ __launch_bounds__(256) void lstm_seq_kernel(
    const float* __restrict__ xz,      // [TC][2560][64]
    const float* __restrict__ Upg,     // [160][640][16] pre-transposed (k-major)
    const float* __restrict__ hinit,   // [640][64] carry-in (prev chunk tail / zeros)
    float* __restrict__ c_st,          // [640][64]
    const int* __restrict__ lens,      // [64]
    float* __restrict__ hc_out,        // [TC][640][64]; doubles as h publish chain
    int t0,
    unsigned* __restrict__ bar,
    unsigned bar_base)
{
    const int tid  = threadIdx.x;
    const int d0   = blockIdx.x * 4;
    const int ks   = tid >> 6;               // 0..3 (wave = k-slice)
    const int kbeg = ks * 160;
    const int lane   = tid & 63;
    const int n_grp  = lane >> 4;            // 0..3
    const int n_base = n_grp * 4;            // 0,4,8,12
    const int b0     = (lane & 15) * 4;      // 0,4,..,60

    __shared__ float U_lds[640 * 16];        // 40 KB, k-major [k][n16]
    __shared__ float red[64][64];            // 16 KB: [n16*4+ks][b ^ (n_grp<<2)]

    // stage this block's U slice to LDS once (linear 40 KB float4 copy)
    {
        const float4* upg = (const float4*)(Upg + (size_t)blockIdx.x * (640 * 16));
        float4* udst = (float4*)U_lds;
#pragma unroll
        for (int it = 0; it < 10; ++it)
            udst[it * 256 + tid] = upg[it * 256 + tid];
    }

    // epilogue-private state: all 256 threads own one (d,b) cell
    const int ed = d0 + (tid >> 6);
    const int eb = tid & 63;
    float c_reg   = c_st[ed * 64 + eb];
    const int len_b = lens[eb];

    __syncthreads();                         // U_lds ready

    float acc[16];                           // [i-row 0..3][q-col 0..3]
    float HA[16], HB[16], HC[16];            // 4k x 4b each
    float UA[16], UB[16], UC[16];            // 4k x 4n each

#define HLOAD(HH)                                                           \
    _Pragma("unroll")                                                       \
    for (int j = 0; j < 4; ++j)                                             \
        *(float4*)&HH[j * 4] = *(const float4*)(hrun + j * 64);             \
    hrun += 256;

#define ULOAD(UU)                                                           \
    _Pragma("unroll")                                                       \
    for (int j = 0; j < 4; ++j)                                             \
        *(float4*)&UU[j * 4] = *(const float4*)(urun + j * 16);             \
    urun += 64;

#define FMAG(HH, UU)                                                        \
    _Pragma("unroll")                                                       \
    for (int j = 0; j < 4; ++j)                                             \
        _Pragma("unroll")                                                   \
        for (int i = 0; i < 4; ++i)                                         \
            _Pragma("unroll")                                               \
            for (int q = 0; q < 4; ++q)                                     \
                acc[i * 4 + q] += UU[j * 4 + i] * HH[j * 4 + q];

#pragma unroll 1
    for (int tl = 0; tl < TC; ++tl) {
        const int t = t0 + tl;
        const float* hprev = (tl == 0) ? hinit
                           : hc_out + (size_t)(tl - 1) * (D_ * 64);
        float*       hcur  = hc_out + (size_t)tl * (D_ * 64);

        // prefetch epilogue operands early -> latency hidden under k-loop
        float xzv[4];
        {
            const float* xzp = xz + (size_t)tl * (L4_ * 64) + eb;
#pragma unroll
            for (int g = 0; g < 4; ++g)
                xzv[g] = xzp[(size_t)(ed + 640 * g) * 64];
        }
        const float hp_epi = hprev[ed * 64 + eb];

#pragma unroll
        for (int i = 0; i < 16; ++i) acc[i] = 0.f;

        const float* hrun = hprev + (size_t)kbeg * 64 + b0;
        const float* urun = &U_lds[(size_t)kbeg * 16 + n_base];

        // 3-stage pipeline over 40 groups of 4 k
        HLOAD(HA) ULOAD(UA)
        HLOAD(HB) ULOAD(UB)
        HLOAD(HC) ULOAD(UC)
#pragma unroll 1
        for (int t3 = 0; t3 < 12; ++t3) {
            FMAG(HA, UA) HLOAD(HA) ULOAD(UA)
            FMAG(HB, UB) HLOAD(HB) ULOAD(UB)
            FMAG(HC, UC) HLOAD(HC) ULOAD(UC)
        }
        FMAG(HA, UA) HLOAD(HA) ULOAD(UA)     // compute g=36, load g=39
        FMAG(HB, UB)                          // g=37
        FMAG(HC, UC)                          // g=38
        FMAG(HA, UA)                          // g=39

        // partials -> red with XOR-swizzled column (conflict-free)
        {
            const int colw = b0 ^ (n_grp << 2);
#pragma unroll
            for (int i = 0; i < 4; ++i)
                *(float4*)&red[((n_base + i) << 2) | ks][colw] = *(float4*)&acc[i * 4];
        }
        __syncthreads();

        {
            const int dd = tid >> 6;
            const int colr = eb ^ (dd << 2);
            float z[4];
#pragma unroll
            for (int g = 0; g < 4; ++g) {
                const int r = ((dd * 4 + g) << 2);
                z[g] = red[r][colr] + red[r + 1][colr] + red[r + 2][colr]
                     + red[r + 3][colr] + xzv[g];
            }
            float ig = 1.f / (1.f + __expf(-z[0]));
            float fg = 1.f / (1.f + __expf(-z[1]));
            float gg = tanhf(z[2]);
            float og = 1.f / (1.f + __expf(-z[3]));
            float c_new = fg * c_reg + ig * gg;
            float h_new = og * tanhf(c_new);
            bool msk = t < len_b;
            float h_out = msk ? h_new : hp_epi;
            c_reg = msk ? c_new : c_reg;
            stg_llc(hcur + ed * 64 + eb, h_out);   // single sc1 publish store
        }

        if (tl != TC - 1)
            grid_barrier(bar, bar_base + (unsigned)tl + 1u);
    }
    c_st[ed * 64 + eb] = c_reg;             // persist c for next chunk
#undef HLOAD
#undef ULOAD
#undef FMAG
}

// ---------------------------------------------------------------------------
// Transpose chunk h1c [tl][d][b] -> out [b][t0+tl][d]   (unchanged)
// ---------------------------------------------------------------------------
__global__ __launch_bounds__(256) void transpose_kernel(
    const float* __restrict__ h1c, float* __restrict__ out, int t0)
{
    const int tl   = blockIdx.x;
    const int dblk = blockIdx.y;
    __shared__ float tile[64][65];

    const int r  = threadIdx.x >> 2;
    const int cq = threadIdx.x & 3;

    const float* src = h1c + (size_t)tl * (D_ * 64) + (size_t)(dblk * 64 + r) * 64 + cq * 16;
#pragma unroll
    for (int j = 0; j < 4; ++j) {
        float4 v = *(const float4*)(src + j * 4);
        tile[r][cq * 16 + j * 4 + 0] = v.x;
        tile[r][cq * 16 + j * 4 + 1] = v.y;
        tile[r][cq * 16 + j * 4 + 2] = v.z;
        tile[r][cq * 16 + j * 4 + 3] = v.w;
    }
    __syncthreads();

    float* dst = out + (size_t)r * (U_ * D_) + (size_t)(t0 + tl) * D_ + dblk * 64 + cq * 16;
#pragma unroll
    for (int j = 0; j < 4; ++j) {
        float4 w;
        w.x = tile[cq * 16 + j * 4 + 0][r];
        w.y = tile[cq * 16 + j * 4 + 1][r];
        w.z = tile[cq * 16 + j * 4 + 2][r];
        w.w = tile[cq * 16 + j * 4 + 3][r];
        *(float4*)(dst + j * 4) = w;
    }
}

// ---------------------------------------------------------------------------
extern "C" void kernel_launch(void* const* d_in, const int* in_sizes, int n_in,
                              void* d_out, int out_size, void* d_ws, size_t ws_size,
                              hipStream_t stream)
{
    const int*   targets = (const int*)d_in[0];
    const int*   lens    = (const int*)d_in[1];
    const float* embed   = (const float*)d_in[2];
    const float* W0      = (const float*)d_in[3];
    const float* U0      = (const float*)d_in[4];
    const float* b0      = (const float*)d_in[5];
    const float* W1      = (const float*)d_in[6];
    const float* U1      = (const float*)d_in[7];
    const float* b1      = (const float*)d_in[8];
    float* out = (float*)d_out;
    float* ws  = (float*)d_ws;

    // workspace layout (floats)
    float* xz  = ws;                                   // TC*2560*64 = 10,485,760
    float* h0c = xz  + (size_t)TC * L4_ * 64;          // TC*640*64  =  2,621,440
    float* h1c = h0c + (size_t)TC * D_ * 64;           // TC*640*64
    float* st  = h1c + (size_t)TC * D_ * 64;           // 6 * 40,960 state buffers
    float* hzero = st;                                 // zero carry-in for chunk 0
    float* c0  = st + 2 * 40960;
    float* c1  = st + 5 * 40960;
    unsigned* bar = (unsigned*)(st + 6 * 40960);       // 512 uints (9 x 128B lines used)
    float* Up0 = st + 6 * 40960 + 512;                 // 640*2560 (64B-aligned)
    float* Up1 = Up0 + (size_t)D_ * L4_;               // 640*2560
    // total ~19.25M floats ~= 77 MB (same as verified layout)

    // zero-init states + barrier words (ws is poisoned before every call)
    hipMemsetAsync(st, 0, (size_t)6 * 40960 * sizeof(float) + 2048, stream);

    // one-time recurrent-weight transpose for both layers (k-major layout)
    prep_up_kernel<<<dim3(D_, 2), dim3(256), 0, stream>>>(U0, U1, Up0, Up1);

    const dim3 gemm_grid(TC * 64 / 128, L4_ / 128);    // (32, 20)
    const dim3 blk(256);

    unsigned launch_idx = 0;
    for (int ch = 0; ch < NCH; ++ch) {
        const int t0 = ch * TC;
        const float* hinit0 = (ch == 0) ? hzero : h0c + (size_t)(TC - 1) * (D_ * 64);
        const float* hinit1 = (ch == 0) ? hzero : h1c + (size_t)(TC - 1) * (D_ * 64);

        // layer 0 input transform: xz = embed[targets] @ W0 + b0
        gemm_kernel<0><<<gemm_grid, blk, 0, stream>>>(embed, targets, W0, b0, xz, E_, t0);

        // layer 0: 64 timesteps in one persistent launch
        lstm_seq_kernel<<<dim3(NBLK), blk, 0, stream>>>(
            xz, Up0, hinit0, c0, lens, h0c, t0, bar, launch_idx * 63u);
        ++launch_idx;

        // layer 1 input transform: xz = h0c @ W1 + b1
        gemm_kernel<1><<<gemm_grid, blk, 0, stream>>>(h0c, targets, W1, b1, xz, D_, t0);

        // layer 1: 64 timesteps in one persistent launch
        lstm_seq_kernel<<<dim3(NBLK), blk, 0, stream>>>(
            xz, Up1, hinit1, c1, lens, h1c, t0, bar, launch_idx * 63u);
        ++launch_idx;

        // emit chunk to output
        transpose_kernel<<<dim3(TC, 10), blk, 0, stream>>>(h1c, out, t0);
    }
}

// Round 11
// 21021.417 us; speedup vs baseline: 1.3716x; 1.0223x over previous
//
#include <hip/hip_runtime.h>
#include <math.h>

// Problem constants
#define B_   64
#define U_   1024
#define E_   512
#define D_   640
#define L4_  2560
#define TC   64          // time-chunk length
#define NCH  16          // number of chunks (TC*NCH == U_)
#define NBLK 160         // persistent blocks (4 d's each); 160 <= 256 CUs -> co-resident
#define SUBQ (NBLK / 8)  // blocks per sub-counter

// ---------------------------------------------------------------------------
// GEMM: C[t][n][b] = bias[n] + sum_k A[m][k] * W[k][n],  m = t*64 + b
// (unchanged, harness-verified)
// ---------------------------------------------------------------------------
template <int MODE>
__global__ __launch_bounds__(256) void gemm_kernel(
    const float* __restrict__ A,        // MODE0: embed [V][E]; MODE1: h0c [TC][640][64]
    const int*   __restrict__ targets,  // [B][U], used in MODE0
    const float* __restrict__ Wm,       // [K][2560]
    const float* __restrict__ bias,     // [2560]
    float* __restrict__ xz,             // [TC][2560][64]
    int K, int t0)
{
    const int tid = threadIdx.x;
    const int m0 = blockIdx.x * 128;
    const int n0 = blockIdx.y * 128;

    __shared__ float As[8][132];
    __shared__ float Bs[8][132];

    float acc[8][8];
#pragma unroll
    for (int i = 0; i < 8; ++i)
#pragma unroll
        for (int j = 0; j < 8; ++j) acc[i][j] = 0.f;

    const float* a_ptr;
    int a_ml = 0, a_kq = 0, a_k = 0;
    if (MODE == 0) {
        a_ml = tid & 127;
        a_kq = (tid >> 7) * 4;
        int m  = m0 + a_ml;
        int b  = m & 63;
        int tl = m >> 6;
        int idx = targets[b * U_ + t0 + tl];
        a_ptr = A + (size_t)idx * E_ + a_kq;
    } else {
        a_k  = tid >> 5;
        a_ml = (tid & 31) * 4;
        int m  = m0 + a_ml;
        int b  = m & 63;
        int tl = m >> 6;
        a_ptr = A + (size_t)tl * (D_ * 64) + (size_t)a_k * 64 + b;
    }
    const int b_k  = tid >> 5;
    const int b_n4 = (tid & 31) * 4;

    const int tx = tid & 15;
    const int ty = tid >> 4;

    for (int k0 = 0; k0 < K; k0 += 8) {
        if (MODE == 0) {
            float4 av = *(const float4*)(a_ptr + k0);
            As[a_kq + 0][a_ml] = av.x;
            As[a_kq + 1][a_ml] = av.y;
            As[a_kq + 2][a_ml] = av.z;
            As[a_kq + 3][a_ml] = av.w;
        } else {
            float4 av = *(const float4*)(a_ptr + (size_t)k0 * 64);
            *(float4*)&As[a_k][a_ml] = av;
        }
        {
            float4 bv = *(const float4*)(Wm + (size_t)(k0 + b_k) * L4_ + n0 + b_n4);
            *(float4*)&Bs[b_k][b_n4] = bv;
        }
        __syncthreads();

#pragma unroll
        for (int k = 0; k < 8; ++k) {
            float af[8], bf[8];
            *(float4*)&af[0] = *(const float4*)&As[k][ty * 8];
            *(float4*)&af[4] = *(const float4*)&As[k][ty * 8 + 4];
            *(float4*)&bf[0] = *(const float4*)&Bs[k][tx * 8];
            *(float4*)&bf[4] = *(const float4*)&Bs[k][tx * 8 + 4];
#pragma unroll
            for (int i = 0; i < 8; ++i)
#pragma unroll
                for (int j = 0; j < 8; ++j) acc[i][j] += af[i] * bf[j];
        }
        __syncthreads();
    }

#pragma unroll
    for (int i = 0; i < 8; ++i) {
        int m  = m0 + ty * 8 + i;
        int tl = m >> 6;
        int b  = m & 63;
        float* outp = xz + (size_t)tl * (L4_ * 64) + b;
#pragma unroll
        for (int j = 0; j < 8; ++j) {
            int n = n0 + tx * 8 + j;
            outp[(size_t)n * 64] = acc[i][j] + bias[n];
        }
    }
}

// ---------------------------------------------------------------------------
// Pre-transpose recurrent weights, K-MAJOR per block:
//   Up[g][k][n16] = Uw[k][gate*640 + (g*4+dd)],  n16 = dd*4 + gate
// (unchanged from round 10 — harness-verified)
// ---------------------------------------------------------------------------
__global__ __launch_bounds__(256) void prep_up_kernel(
    const float* __restrict__ U0w, const float* __restrict__ U1w,
    float* __restrict__ Up0, float* __restrict__ Up1)
{
    const int k = blockIdx.x;                       // 0..639
    const float* Uw = blockIdx.y ? U1w : U0w;
    float*       Up = blockIdx.y ? Up1 : Up0;
    for (int d = threadIdx.x; d < D_; d += 256) {   // coalesced reads over d
        const int g  = d >> 2;
        const int dd = d & 3;
#pragma unroll
        for (int gate = 0; gate < 4; ++gate) {
            float v = Uw[(size_t)k * L4_ + gate * 640 + d];
            Up[((size_t)g * 640 + k) * 16 + dd * 4 + gate] = v;
        }
    }
}

// ---------------------------------------------------------------------------
// LLC write-through store (sc1, agent scope) — h publish. (r9/r10-verified)
// ---------------------------------------------------------------------------
__device__ __forceinline__ void stg_llc(float* p, float v) {
    __hip_atomic_store(p, v, __ATOMIC_RELAXED, __HIP_MEMORY_SCOPE_AGENT);
}

// ---------------------------------------------------------------------------
// Two-level, monotonic (no-reset) grid barrier. Proven rounds 3/6/7/9/10.
// ---------------------------------------------------------------------------
__device__ __forceinline__ void grid_barrier(unsigned* bar, unsigned done)
{
    asm volatile("s_waitcnt vmcnt(0)" ::: "memory");
    __syncthreads();
    if (threadIdx.x == 0) {
        unsigned* sub    = bar + ((blockIdx.x & 7) << 5);   // 128B-separated lines
        unsigned* master = bar + (8 << 5);
        unsigned a = __hip_atomic_fetch_add(sub, 1u, __ATOMIC_RELAXED, __HIP_MEMORY_SCOPE_AGENT);
        if (a == done * SUBQ - 1u)
            __hip_atomic_fetch_add(master, 1u, __ATOMIC_RELAXED, __HIP_MEMORY_SCOPE_AGENT);
        const unsigned tgt = done * 8u;
        while (__hip_atomic_load(master, __ATOMIC_RELAXED, __HIP_MEMORY_SCOPE_AGENT) < tgt)
            __builtin_amdgcn_s_sleep(1);
    }
    __syncthreads();
}

// ---------------------------------------------------------------------------
// Persistent LSTM sequence kernel, round 11: r10 geometry + 2 waves/SIMD.
// Grid: 160 blocks x 512 threads (8 waves = 8 k-slices of 80).
// r10 post-mortem: at 1 wave/SIMD the DS(3.2us)+VMEM(4.3us)+barrier(1.4us)
// budgets SUM (8.35us measured) because a lone wave's waitcnt stalls leave
// the SIMD idle. 8 waves = 2/SIMD interleave stalls; per-CU operand traffic
// and per-SIMD VALU floor are unchanged by the split (both invariant in KS).
// Thread tile stays balanced 4n x 4b; red[] grows to [128][64] (8 partials).
// ---------------------------------------------------------------------------
__global__ __launch_bounds__(512) void lstm_seq_kernel(
    const float* __restrict__ xz,      // [TC][2560][64]
    const float* __restrict__ Upg,     // [160][640][16] pre-transposed (k-major)
    const float* __restrict__ hinit,   // [640][64] carry-in (prev chunk tail / zeros)
    float* __restrict__ c_st,          // [640][64]
    const int* __restrict__ lens,      // [64]
    float* __restrict__ hc_out,        // [TC][640][64]; doubles as h publish chain
    int t0,
    unsigned* __restrict__ bar,
    unsigned bar_base)
{
    const int tid  = threadIdx.x;
    const int d0   = blockIdx.x * 4;
    const int ks   = tid >> 6;               // 0..7 (wave = k-slice of 80)
    const int kbeg = ks * 80;
    const int lane   = tid & 63;
    const int n_grp  = lane >> 4;            // 0..3
    const int n_base = n_grp * 4;            // 0,4,8,12
    const int b0     = (lane & 15) * 4;      // 0,4,..,60

    __shared__ float U_lds[640 * 16];        // 40 KB, k-major [k][n16]
    __shared__ float red[128][64];           // 32 KB: [n16*8+ks][b ^ (n_grp<<2)]

    // stage this block's U slice to LDS once (linear 40 KB float4 copy)
    {
        const float4* upg = (const float4*)(Upg + (size_t)blockIdx.x * (640 * 16));
        float4* udst = (float4*)U_lds;
#pragma unroll
        for (int it = 0; it < 5; ++it)
            udst[it * 512 + tid] = upg[it * 512 + tid];
    }

    // epilogue-private state: threads 0..255 own one (d,b) cell
    const bool epi = tid < 256;
    const int ed = d0 + ((tid >> 6) & 3);
    const int eb = tid & 63;
    float c_reg = 0.f;
    int   len_b = 0;
    if (epi) {
        c_reg = c_st[ed * 64 + eb];
        len_b = lens[eb];
    }

    __syncthreads();                         // U_lds ready

    float acc[16];                           // [i-row 0..3][q-col 0..3]
    float HA[16], HB[16], HC[16];            // 4k x 4b each
    float UA[16], UB[16], UC[16];            // 4k x 4n each

#define HLOAD(HH)                                                           \
    _Pragma("unroll")                                                       \
    for (int j = 0; j < 4; ++j)                                             \
        *(float4*)&HH[j * 4] = *(const float4*)(hrun + j * 64);             \
    hrun += 256;

#define ULOAD(UU)                                                           \
    _Pragma("unroll")                                                       \
    for (int j = 0; j < 4; ++j)                                             \
        *(float4*)&UU[j * 4] = *(const float4*)(urun + j * 16);             \
    urun += 64;

#define FMAG(HH, UU)                                                        \
    _Pragma("unroll")                                                       \
    for (int j = 0; j < 4; ++j)                                             \
        _Pragma("unroll")                                                   \
        for (int i = 0; i < 4; ++i)                                         \
            _Pragma("unroll")                                               \
            for (int q = 0; q < 4; ++q)                                     \
                acc[i * 4 + q] += UU[j * 4 + i] * HH[j * 4 + q];

#pragma unroll 1
    for (int tl = 0; tl < TC; ++tl) {
        const int t = t0 + tl;
        const float* hprev = (tl == 0) ? hinit
                           : hc_out + (size_t)(tl - 1) * (D_ * 64);
        float*       hcur  = hc_out + (size_t)tl * (D_ * 64);

        // prefetch epilogue operands early -> latency hidden under k-loop
        float xzv[4];
        float hp_epi = 0.f;
        if (epi) {
            const float* xzp = xz + (size_t)tl * (L4_ * 64) + eb;
#pragma unroll
            for (int g = 0; g < 4; ++g)
                xzv[g] = xzp[(size_t)(ed + 640 * g) * 64];
            hp_epi = hprev[ed * 64 + eb];
        }

#pragma unroll
        for (int i = 0; i < 16; ++i) acc[i] = 0.f;

        const float* hrun = hprev + (size_t)kbeg * 64 + b0;
        const float* urun = &U_lds[(size_t)kbeg * 16 + n_base];

        // 3-stage pipeline over 20 groups of 4 k
        HLOAD(HA) ULOAD(UA)
        HLOAD(HB) ULOAD(UB)
        HLOAD(HC) ULOAD(UC)
#pragma unroll 1
        for (int t3 = 0; t3 < 5; ++t3) {     // computes G0..G14, loads G3..G17
            FMAG(HA, UA) HLOAD(HA) ULOAD(UA)
            FMAG(HB, UB) HLOAD(HB) ULOAD(UB)
            FMAG(HC, UC) HLOAD(HC) ULOAD(UC)
        }
        FMAG(HA, UA) HLOAD(HA) ULOAD(UA)     // G15; load G18
        FMAG(HB, UB) HLOAD(HB) ULOAD(UB)     // G16; load G19
        FMAG(HC, UC)                          // G17
        FMAG(HA, UA)                          // G18
        FMAG(HB, UB)                          // G19

        // partials -> red with XOR-swizzled column
        {
            const int colw = b0 ^ (n_grp << 2);
#pragma unroll
            for (int i = 0; i < 4; ++i)
                *(float4*)&red[((n_base + i) << 3) | ks][colw] = *(float4*)&acc[i * 4];
        }
        __syncthreads();

        if (epi) {
            const int dd = (tid >> 6) & 3;
            const int colr = eb ^ (dd << 2);
            float z[4];
#pragma unroll
            for (int g = 0; g < 4; ++g) {
                const int r = ((dd * 4 + g) << 3);
                float s = 0.f;
#pragma unroll
                for (int kk = 0; kk < 8; ++kk) s += red[r + kk][colr];
                z[g] = s + xzv[g];
            }
            float ig = 1.f / (1.f + __expf(-z[0]));
            float fg = 1.f / (1.f + __expf(-z[1]));
            float gg = tanhf(z[2]);
            float og = 1.f / (1.f + __expf(-z[3]));
            float c_new = fg * c_reg + ig * gg;
            float h_new = og * tanhf(c_new);
            bool msk = t < len_b;
            float h_out = msk ? h_new : hp_epi;
            c_reg = msk ? c_new : c_reg;
            stg_llc(hcur + ed * 64 + eb, h_out);   // single sc1 publish store
        }

        if (tl != TC - 1)
            grid_barrier(bar, bar_base + (unsigned)tl + 1u);
    }
    if (epi) c_st[ed * 64 + eb] = c_reg;     // persist c for next chunk
#undef HLOAD
#undef ULOAD
#undef FMAG
}

// ---------------------------------------------------------------------------
// Transpose chunk h1c [tl][d][b] -> out [b][t0+tl][d]   (unchanged)
// ---------------------------------------------------------------------------
__global__ __launch_bounds__(256) void transpose_kernel(
    const float* __restrict__ h1c, float* __restrict__ out, int t0)
{
    const int tl   = blockIdx.x;
    const int dblk = blockIdx.y;
    __shared__ float tile[64][65];

    const int r  = threadIdx.x >> 2;
    const int cq = threadIdx.x & 3;

    const float* src = h1c + (size_t)tl * (D_ * 64) + (size_t)(dblk * 64 + r) * 64 + cq * 16;
#pragma unroll
    for (int j = 0; j < 4; ++j) {
        float4 v = *(const float4*)(src + j * 4);
        tile[r][cq * 16 + j * 4 + 0] = v.x;
        tile[r][cq * 16 + j * 4 + 1] = v.y;
        tile[r][cq * 16 + j * 4 + 2] = v.z;
        tile[r][cq * 16 + j * 4 + 3] = v.w;
    }
    __syncthreads();

    float* dst = out + (size_t)r * (U_ * D_) + (size_t)(t0 + tl) * D_ + dblk * 64 + cq * 16;
#pragma unroll
    for (int j = 0; j < 4; ++j) {
        float4 w;
        w.x = tile[cq * 16 + j * 4 + 0][r];
        w.y = tile[cq * 16 + j * 4 + 1][r];
        w.z = tile[cq * 16 + j * 4 + 2][r];
        w.w = tile[cq * 16 + j * 4 + 3][r];
        *(float4*)(dst + j * 4) = w;
    }
}

// ---------------------------------------------------------------------------
extern "C" void kernel_launch(void* const* d_in, const int* in_sizes, int n_in,
                              void* d_out, int out_size, void* d_ws, size_t ws_size,
                              hipStream_t stream)
{
    const int*   targets = (const int*)d_in[0];
    const int*   lens    = (const int*)d_in[1];
    const float* embed   = (const float*)d_in[2];
    const float* W0      = (const float*)d_in[3];
    const float* U0      = (const float*)d_in[4];
    const float* b0      = (const float*)d_in[5];
    const float* W1      = (const float*)d_in[6];
    const float* U1      = (const float*)d_in[7];
    const float* b1      = (const float*)d_in[8];
    float* out = (float*)d_out;
    float* ws  = (float*)d_ws;

    // workspace layout (floats)
    float* xz  = ws;                                   // TC*2560*64 = 10,485,760
    float* h0c = xz  + (size_t)TC * L4_ * 64;          // TC*640*64  =  2,621,440
    float* h1c = h0c + (size_t)TC * D_ * 64;           // TC*640*64
    float* st  = h1c + (size_t)TC * D_ * 64;           // 6 * 40,960 state buffers
    float* hzero = st;                                 // zero carry-in for chunk 0
    float* c0  = st + 2 * 40960;
    float* c1  = st + 5 * 40960;
    unsigned* bar = (unsigned*)(st + 6 * 40960);       // 512 uints (9 x 128B lines used)
    float* Up0 = st + 6 * 40960 + 512;                 // 640*2560 (64B-aligned)
    float* Up1 = Up0 + (size_t)D_ * L4_;               // 640*2560
    // total ~19.25M floats ~= 77 MB (same as verified layout)

    // zero-init states + barrier words (ws is poisoned before every call)
    hipMemsetAsync(st, 0, (size_t)6 * 40960 * sizeof(float) + 2048, stream);

    // one-time recurrent-weight transpose for both layers (k-major layout)
    prep_up_kernel<<<dim3(D_, 2), dim3(256), 0, stream>>>(U0, U1, Up0, Up1);

    const dim3 gemm_grid(TC * 64 / 128, L4_ / 128);    // (32, 20)
    const dim3 blk(256);
    const dim3 blk_seq(512);

    unsigned launch_idx = 0;
    for (int ch = 0; ch < NCH; ++ch) {
        const int t0 = ch * TC;
        const float* hinit0 = (ch == 0) ? hzero : h0c + (size_t)(TC - 1) * (D_ * 64);
        const float* hinit1 = (ch == 0) ? hzero : h1c + (size_t)(TC - 1) * (D_ * 64);

        // layer 0 input transform: xz = embed[targets] @ W0 + b0
        gemm_kernel<0><<<gemm_grid, blk, 0, stream>>>(embed, targets, W0, b0, xz, E_, t0);

        // layer 0: 64 timesteps in one persistent launch
        lstm_seq_kernel<<<dim3(NBLK), blk_seq, 0, stream>>>(
            xz, Up0, hinit0, c0, lens, h0c, t0, bar, launch_idx * 63u);
        ++launch_idx;

        // layer 1 input transform: xz = h0c @ W1 + b1
        gemm_kernel<1><<<gemm_grid, blk, 0, stream>>>(h0c, targets, W1, b1, xz, D_, t0);

        // layer 1: 64 timesteps in one persistent launch
        lstm_seq_kernel<<<dim3(NBLK), blk_seq, 0, stream>>>(
            xz, Up1, hinit1, c1, lens, h1c, t0, bar, launch_idx * 63u);
        ++launch_idx;

        // emit chunk to output
        transpose_kernel<<<dim3(TC, 10), blk, 0, stream>>>(h1c, out, t0);
    }
}